// Round 17
// baseline (75.265 us; speedup 1.0000x reference)
//
#include <hip/hip_runtime.h>

// ---------------------------------------------------------------------------
// TwoLayerGCN on MI355X (gfx950).  B=4, N=2048, F=128, H=256, C=64.
//
//   d_i = rsqrt(nnz_i + 1) ; w_ij = [A_ij>0] exp(lrelu(fs_i+fd_j)) d_j (1+[i==j])
//   rs_i = sum_j [A_ij>0] exp(lrelu(fs_i+fd_j))
//   layer1: out1 = relu( (d_i/rs_i)(W@X)@W1 + b1 )
//   layer2: node = (d_i/rs_i) W2mat@(out1@W2) + b2 ; graph = sum_i node
//
// R9:  dense MFMA SpMM (operand swap, w in regs), zero barriers in K-loop.
// R15: de-dup MKW (8-way K-split). R16: factored exp2 (per-node quads) +
//      v_cvt_pk_bf16_f32 pack -> 62.3us. Bound = dependency stalls at the
//      fixed 2 waves/SIMD (256 blocks = 1 block/CU).
// R17: 16-row tiles -> 512 blocks = 2 blocks/CU = 4 waves/SIMD (real
//      occupancy doubling; R13's attempt failed because grid stayed 256).
//      acc[8][1] (32 VGPR) fits 128-VGPR/4-wave budget; kdense1 LDS ~71KB,
//      kdense2 ~54KB (2 blocks/CU). Epilogue: GEMM1 all waves; GEMM2
//      (waves 0-3, half-tile OW2f via i0&16) || dots2 (waves 4-7).
//      Cost accepted: XTf panel L2 re-reads double (overlappable).
// ---------------------------------------------------------------------------

typedef __attribute__((ext_vector_type(8))) short  s16x8;
typedef __attribute__((ext_vector_type(4))) float  f32x4;
typedef unsigned short u16;
typedef unsigned int   u32;
typedef unsigned long long u64;

#define LOG2E 1.4426950408889634f
#define NB 4
#define NN 2048
#define NF 128
#define NH 256
#define NC 64

__device__ __forceinline__ u16 f2bf(float f) {
    u32 x = __builtin_bit_cast(u32, f);
    return (u16)((x + 0x7fffu + ((x >> 16) & 1u)) >> 16);
}

// ---- kpre: block-role dispatch ---------------------------------------------
// [0,256): X-tiles -> XTf (frag-tiled bf16) + layer1 dots (FS1, FDD1 quad 0-2).
// [256,260): W1T/W2T transposes.
// [260,260+8192): stats: A read (uint4) -> bm bitmask, d -> FDD1/FDD2 quad 3.
__global__ void kpre(const float* __restrict__ X, const float* __restrict__ A,
                     const float* __restrict__ a1s, const float* __restrict__ a1d,
                     const float* __restrict__ W1, const float* __restrict__ W2,
                     u16* __restrict__ XTf, u16* __restrict__ W1T,
                     u16* __restrict__ W2T, float* __restrict__ FS1,
                     float* __restrict__ FDD1, float* __restrict__ FDD2,
                     u64* __restrict__ bm) {
    const int bid = blockIdx.x;
    const int t = threadIdx.x;
    if (bid >= NB * 64 + 4) {                 // ---- stats role ----
        __shared__ int redi[4];
        int row = bid - (NB * 64 + 4);        // 0..8191
        const float* Arow = A + (size_t)row * NN;
        int l = t & 63, wv = t >> 6;
        int deg = 0;
#pragma unroll
        for (int e = 0; e < 2; e++) {
            uint4 av = *(const uint4*)&Arow[e * 1024 + t * 4];
            u32 nib = (av.x ? 1u : 0u) | (av.y ? 2u : 0u) |
                      (av.z ? 4u : 0u) | (av.w ? 8u : 0u);
            deg += (int)__popc(nib);
            u32 o1 = __shfl_xor(nib, 1);  u32 byt = nib | (o1 << 4);
            u32 o2 = __shfl_xor(byt, 2);  u32 h16 = byt | (o2 << 8);
            u32 o4 = __shfl_xor(h16, 4);  u32 w32 = h16 | (o4 << 16);
            u32 o8 = __shfl_xor(w32, 8);
            u64 w64 = (u64)w32 | ((u64)o8 << 32);
            if ((l & 15) == 0)
                bm[(size_t)row * 32 + e * 16 + wv * 4 + (l >> 4)] = w64;
        }
#pragma unroll
        for (int o = 32; o > 0; o >>= 1) deg += __shfl_down(deg, o);
        if (l == 0) redi[wv] = deg;
        __syncthreads();
        if (t == 0) {
            int s = redi[0] + redi[1] + redi[2] + redi[3];
            float d = rsqrtf((float)s + 1.0f);
            FDD1[4 * row + 3] = d;
            FDD2[4 * row + 3] = d;
        }
        return;
    }
    if (bid >= NB * 64) {                     // ---- weight role ----
        int tt = (bid - NB * 64) * 256 + t;
        for (int i = tt; i < NF * NH; i += 1024) {
            int k = i >> 8, c = i & 255;
            W1T[c * NF + k] = f2bf(W1[i]);
        }
        for (int i = tt; i < NH * NC; i += 1024) {
            int k = i >> 6, c = i & 63;
            W2T[c * NH + k] = f2bf(W2[i]);
        }
        return;
    }
    // ---- X role: 32 nodes (one k-block) ----
    __shared__ float tile[32][132];
    __shared__ float asb[NF], adb[NF];
    __shared__ float dred[32][8][2];
    const int b = bid >> 6, i0 = (bid & 63) * 32;
    if (t < 128) asb[t] = a1s[t];
    else         adb[t - 128] = a1d[t - 128];
    for (int i = t; i < 32 * NF / 4; i += 256) {
        int r = (i * 4) >> 7, c = (i * 4) & 127;
        *(float4*)&tile[r][c] = *(const float4*)&X[((size_t)b * NN + i0 + r) * NF + c];
    }
    __syncthreads();
    {   // layer1 dots
        int r = t >> 3, ch = t & 7;
        float ps = 0.f, pd = 0.f;
#pragma unroll
        for (int q = 0; q < 16; q++) {
            float x = tile[r][ch * 16 + q];
            ps += x * asb[ch * 16 + q];
            pd += x * adb[ch * 16 + q];
        }
        dred[r][ch][0] = ps; dred[r][ch][1] = pd;
    }
    {   // XTf frag-tiled write: frag f holds feats 16f..16f+15, tile [li][32 k]
        int f = t >> 5, li = (t >> 1) & 15, half = t & 1;
        __attribute__((aligned(16))) u16 tmp[16];
#pragma unroll
        for (int k = 0; k < 16; k++)
            tmp[k] = f2bf(tile[half * 16 + k][f * 16 + li]);
        u16* dst = XTf + ((size_t)(b * 8 + f) * 64 + (i0 >> 5)) * 512
                       + li * 32 + half * 16;
        int4* d4 = (int4*)dst;
        const int4* sv = (const int4*)tmp;
        d4[0] = sv[0]; d4[1] = sv[1];
    }
    __syncthreads();
    if (t < 64) {
        int r = t & 31, which = t >> 5;
        float s = 0.f;
#pragma unroll
        for (int ch = 0; ch < 8; ch++) s += dred[r][ch][which];
        int grow = (b << 11) + i0 + r;
        float sf = s * LOG2E;
        if (which == 0) FS1[grow] = sf;
        else {
            FDD1[4 * grow]     = sf;
            FDD1[4 * grow + 1] = exp2f(sf);
            FDD1[4 * grow + 2] = exp2f(0.2f * sf);
        }
    }
}

// w B-fragment: 8 w values for row IR (batch-local), j = jb..jb+7.
#define MKW(FS_, EI_, EI2_, IR_, M_, BW_, RS_) { \
    u32 pk0_, pk1_, pk2_, pk3_; \
    _Pragma("unroll") \
    for (int ee = 0; ee < 4; ee++) { \
        float s0_ = FS_ + fdv[2 * ee],     s1_ = FS_ + fdv[2 * ee + 1]; \
        float e0_ = (s0_ >= 0.f) ? EI_ * ev[2 * ee]     : EI2_ * e2v[2 * ee]; \
        float e1_ = (s1_ >= 0.f) ? EI_ * ev[2 * ee + 1] : EI2_ * e2v[2 * ee + 1]; \
        bool mk0 = (M_ >> (2 * ee)) & 1u, mk1 = (M_ >> (2 * ee + 1)) & 1u; \
        RS_ += mk0 ? e0_ : 0.f;  RS_ += mk1 ? e1_ : 0.f; \
        float w0_ = e0_ * dv[2 * ee], w1_ = e1_ * dv[2 * ee + 1]; \
        if (jb + 2 * ee == IR_)     w0_ *= 2.f; \
        if (jb + 2 * ee + 1 == IR_) w1_ *= 2.f; \
        w0_ = mk0 ? w0_ : 0.f;  w1_ = mk1 ? w1_ : 0.f; \
        u32 pr_; \
        asm("v_cvt_pk_bf16_f32 %0, %1, %2" : "=v"(pr_) : "v"(w0_), "v"(w1_)); \
        if (ee == 0) pk0_ = pr_; else if (ee == 1) pk1_ = pr_; \
        else if (ee == 2) pk2_ = pr_; else pk3_ = pr_; \
    } \
    uint4 pku_ = {pk0_, pk1_, pk2_, pk3_}; \
    BW_ = __builtin_bit_cast(s16x8, pku_); }

#define LOADQ8 \
    float fdv[8], ev[8], e2v[8], dv[8]; \
    _Pragma("unroll") \
    for (int e = 0; e < 8; e++) { \
        float4 ffq = fp4[e]; \
        fdv[e] = ffq.x; ev[e] = ffq.y; e2v[e] = ffq.z; dv[e] = ffq.w; }

// ---- kdense1: layer1 SpMM (16-row tile, 8-way K-split) + epilogue ----------
__global__ __launch_bounds__(512) void kdense1(
    const u64* __restrict__ bm, const float* __restrict__ FS,
    const float* __restrict__ FDD, const u16* __restrict__ XTf,
    const u16* __restrict__ W1T, const u16* __restrict__ W2T,
    const float* __restrict__ b1, const float* __restrict__ a2s,
    const float* __restrict__ a2d, float* __restrict__ FS2,
    float* __restrict__ FDD2, u16* __restrict__ OW2f) {
    const int b = blockIdx.y;
    const int i0 = blockIdx.x * 16;
    const int t = threadIdx.x, wv = t >> 6, l = t & 63;
    const int li = l & 15, q = l >> 4;

    __shared__ __attribute__((aligned(16))) float tpart[4][16][132];  // 33.8KB
    float* o1 = &tpart[0][0][0];            // [16][260] aliases slabs 0-1
    __shared__ __attribute__((aligned(16))) float4 fdpq[2048];        // 32KB
    __shared__ __attribute__((aligned(16))) u32 bmt[16][68];          // 4.4KB
    __shared__ float rsred[8][16];
    __shared__ float rscl[16];
    __shared__ float dredp[512];

    const float* FDDb = FDD + ((size_t)(b << 11) << 2);
    {   // stage fd/E/E2/d quad panel
        const float4* src = (const float4*)FDDb;
        fdpq[t] = src[t];           fdpq[t + 512]  = src[t + 512];
        fdpq[t + 1024] = src[t + 1024]; fdpq[t + 1536] = src[t + 1536];
    }
    if (t < 256) {   // stage bm tile: 16 rows x 256B, padded stride 68 u32
        int r = t >> 4, seg = t & 15;
        const uint4* src = (const uint4*)(bm + ((size_t)((b << 11) + i0 + r)) * 32);
        *(uint4*)&bmt[r][seg * 4] = src[seg];
    }
    __syncthreads();

    const float fs0 = FS[(b << 11) + i0 + li];
    const float Ei0 = exp2f(fs0), Ei20 = exp2f(0.2f * fs0);
    const int irow0 = i0 + li;
    const u16* xfb = XTf + (size_t)b * 8 * 64 * 512;
    const int laneoff = li * 32 + q * 8;      // lane offset within 1KB frag tile

    f32x4 zero = {0.f, 0.f, 0.f, 0.f};
    f32x4 acc[8];
#pragma unroll
    for (int fa = 0; fa < 8; fa++) acc[fa] = zero;
    float rs0 = 0.f;

    for (int st = 0; st < 8; ++st) {
        const int kblk = st * 8 + wv;         // unique k-block per wave
        const int kb = kblk * 32;
        const u16* xt = xfb + (size_t)kblk * 512 + laneoff;
        s16x8 xa0 = *(const s16x8*)(xt);
        s16x8 xa1 = *(const s16x8*)(xt + 1 * 64 * 512);
        s16x8 xa2 = *(const s16x8*)(xt + 2 * 64 * 512);
        s16x8 xa3 = *(const s16x8*)(xt + 3 * 64 * 512);
        s16x8 xa4 = *(const s16x8*)(xt + 4 * 64 * 512);
        s16x8 xa5 = *(const s16x8*)(xt + 5 * 64 * 512);
        s16x8 xa6 = *(const s16x8*)(xt + 6 * 64 * 512);
        s16x8 xa7 = *(const s16x8*)(xt + 7 * 64 * 512);
        const float4* fp4 = (const float4*)&fdpq[kb + q * 8];
        LOADQ8;
        u32 m0 = (bmt[li][kblk] >> (q * 8)) & 0xffu;
        const int jb = kb + q * 8;
        s16x8 bw0;
        MKW(fs0, Ei0, Ei20, irow0, m0, bw0, rs0);
        acc[0] = __builtin_amdgcn_mfma_f32_16x16x32_bf16(xa0, bw0, acc[0], 0, 0, 0);
        acc[1] = __builtin_amdgcn_mfma_f32_16x16x32_bf16(xa1, bw0, acc[1], 0, 0, 0);
        acc[2] = __builtin_amdgcn_mfma_f32_16x16x32_bf16(xa2, bw0, acc[2], 0, 0, 0);
        acc[3] = __builtin_amdgcn_mfma_f32_16x16x32_bf16(xa3, bw0, acc[3], 0, 0, 0);
        acc[4] = __builtin_amdgcn_mfma_f32_16x16x32_bf16(xa4, bw0, acc[4], 0, 0, 0);
        acc[5] = __builtin_amdgcn_mfma_f32_16x16x32_bf16(xa5, bw0, acc[5], 0, 0, 0);
        acc[6] = __builtin_amdgcn_mfma_f32_16x16x32_bf16(xa6, bw0, acc[6], 0, 0, 0);
        acc[7] = __builtin_amdgcn_mfma_f32_16x16x32_bf16(xa7, bw0, acc[7], 0, 0, 0);
    }
    rs0 += __shfl_xor(rs0, 16); rs0 += __shfl_xor(rs0, 32);
    if (l < 16) rsred[wv][l] = rs0;
    // two-round k-reduction: waves 4-7 write slabs 0-3, waves 0-3 accumulate
    if (wv >= 4) {
#pragma unroll
        for (int fa = 0; fa < 8; fa++)
            *(float4*)&tpart[wv - 4][li][fa * 16 + q * 4] =
                (float4){acc[fa][0], acc[fa][1], acc[fa][2], acc[fa][3]};
    }
    __syncthreads();
    if (wv < 4) {
#pragma unroll
        for (int fa = 0; fa < 8; fa++) {
            int co = fa * 16 + q * 4;
            float4 u0 = *(const float4*)&tpart[wv][li][co];
            u0.x += acc[fa][0]; u0.y += acc[fa][1];
            u0.z += acc[fa][2]; u0.w += acc[fa][3];
            *(float4*)&tpart[wv][li][co] = u0;
        }
    }
    __syncthreads();
    if (t < 16) {
        float rsum = 0.f;
#pragma unroll
        for (int w8 = 0; w8 < 8; w8++) rsum += rsred[w8][t];
        rscl[t] = FDDb[4 * (i0 + t) + 3] / fmaxf(rsum, 1e-30f);
    }
    {   // sum 4 slabs into tpart[0]: 16 rows x 128 cols, float4 per thread
        int r = t >> 5, c = (t & 31) * 4;
        float4 v0 = *(const float4*)&tpart[0][r][c];
        float4 v1 = *(const float4*)&tpart[1][r][c];
        float4 v2 = *(const float4*)&tpart[2][r][c];
        float4 v3 = *(const float4*)&tpart[3][r][c];
        v0.x += v1.x + v2.x + v3.x; v0.y += v1.y + v2.y + v3.y;
        v0.z += v1.z + v2.z + v3.z; v0.w += v1.w + v2.w + v3.w;
        *(float4*)&tpart[0][r][c] = v0;
    }
    __syncthreads();
    // ---- epilogue: GEMM1 T@W1 (all waves, 32 cols each) -------------------
    const int c0w = wv * 32;
    f32x4 p00 = zero, p01 = zero;
    for (int k2 = 0; k2 < 4; ++k2) {
        const float* tp = &tpart[0][li][k2 * 32 + q * 8];
        float4 t0 = *(const float4*)tp;
        float4 t1 = *(const float4*)(tp + 4);
        s16x8 aa;
        aa[0] = (short)f2bf(t0.x); aa[1] = (short)f2bf(t0.y);
        aa[2] = (short)f2bf(t0.z); aa[3] = (short)f2bf(t0.w);
        aa[4] = (short)f2bf(t1.x); aa[5] = (short)f2bf(t1.y);
        aa[6] = (short)f2bf(t1.z); aa[7] = (short)f2bf(t1.w);
        s16x8 w0 = *(const s16x8*)&W1T[(size_t)(c0w + li) * NF + k2 * 32 + q * 8];
        s16x8 w1 = *(const s16x8*)&W1T[(size_t)(c0w + 16 + li) * NF + k2 * 32 + q * 8];
        p00 = __builtin_amdgcn_mfma_f32_16x16x32_bf16(aa, w0, p00, 0, 0, 0);
        p01 = __builtin_amdgcn_mfma_f32_16x16x32_bf16(aa, w1, p01, 0, 0, 0);
    }
    __syncthreads();   // tpart[0] reads done; o1 (same region) now writable
#pragma unroll
    for (int r = 0; r < 4; r++) {
        int rr = q * 4 + r;
        float rsc = rscl[rr];
        int ca = c0w + li, cb2 = c0w + 16 + li;
        o1[rr * 260 + ca]  = fmaxf(p00[r] * rsc + b1[ca], 0.f);
        o1[rr * 260 + cb2] = fmaxf(p01[r] * rsc + b1[cb2], 0.f);
    }
    __syncthreads();
    if (wv >= 4) {     // dots2: 16 rows x 16 segs of 16 cols (waves 4-7)
        int idx = t - 256;
        int r = idx >> 4, seg = idx & 15;
        float ps = 0.f, pd = 0.f;
#pragma unroll
        for (int qq = 0; qq < 4; qq++) {
            float4 xv = *(const float4*)&o1[r * 260 + seg * 16 + qq * 4];
            float4 sv = *(const float4*)&a2s[seg * 16 + qq * 4];
            float4 dv2 = *(const float4*)&a2d[seg * 16 + qq * 4];
            ps += xv.x * sv.x + xv.y * sv.y + xv.z * sv.z + xv.w * sv.w;
            pd += xv.x * dv2.x + xv.y * dv2.y + xv.z * dv2.z + xv.w * dv2.w;
        }
        dredp[(r * 16 + seg) * 2]     = ps;
        dredp[(r * 16 + seg) * 2 + 1] = pd;
    } else {           // GEMM2 -> OW2f half-tiles (waves 0-3, col frag nt=wv)
        const int nt = wv;
        f32x4 q0 = zero;
        for (int k2 = 0; k2 < 8; ++k2) {
            int kc = k2 * 32 + q * 8;
            const float* op = &o1[li * 260 + kc];
            float4 v0 = *(const float4*)op;
            float4 v1 = *(const float4*)(op + 4);
            s16x8 aa;
            aa[0] = (short)f2bf(v0.x); aa[1] = (short)f2bf(v0.y);
            aa[2] = (short)f2bf(v0.z); aa[3] = (short)f2bf(v0.w);
            aa[4] = (short)f2bf(v1.x); aa[5] = (short)f2bf(v1.y);
            aa[6] = (short)f2bf(v1.z); aa[7] = (short)f2bf(v1.w);
            s16x8 bb = *(const s16x8*)&W2T[(size_t)(nt * 16 + li) * NH + kc];
            q0 = __builtin_amdgcn_mfma_f32_16x16x32_bf16(aa, bb, q0, 0, 0, 0);
        }
        u16* dst = OW2f + ((size_t)(b * 4 + nt) * 64 + (i0 >> 5)) * 512
                        + li * 32 + (i0 & 16) + q * 4;
        uint2 pk;
        pk.x = (u32)f2bf(q0[0]) | ((u32)f2bf(q0[1]) << 16);
        pk.y = (u32)f2bf(q0[2]) | ((u32)f2bf(q0[3]) << 16);
        *(uint2*)dst = pk;
    }
    __syncthreads();
    if (t < 32) {
        int r = t & 15, which = t >> 4;
        float s = 0.f;
#pragma unroll
        for (int seg = 0; seg < 16; ++seg) s += dredp[(r * 16 + seg) * 2 + which];
        int grow = (b << 11) + i0 + r;
        float sf = s * LOG2E;
        if (which == 0) FS2[grow] = sf;
        else {
            FDD2[4 * grow]     = sf;
            FDD2[4 * grow + 1] = exp2f(sf);
            FDD2[4 * grow + 2] = exp2f(0.2f * sf);
        }
    }
}

// ---- kdense2: layer2 SpMM (16-row tile); node + graph partials -------------
__global__ __launch_bounds__(512) void kdense2(
    const u64* __restrict__ bm, const float* __restrict__ FS,
    const float* __restrict__ FDD, const u16* __restrict__ OW2f,
    const float* __restrict__ b2, float* __restrict__ node,
    float* __restrict__ gpart) {
    const int b = blockIdx.y;
    const int i0 = blockIdx.x * 16;
    const int t = threadIdx.x, wv = t >> 6, l = t & 63;
    const int li = l & 15, q = l >> 4;

    __shared__ __attribute__((aligned(16))) float tp[4][16][68];      // 17.4KB
    __shared__ __attribute__((aligned(16))) float4 fdpq[2048];        // 32KB
    __shared__ __attribute__((aligned(16))) u32 bmt[16][68];          // 4.4KB
    __shared__ float rsred[8][16];
    __shared__ float rscl[16];

    const float* FDDb = FDD + ((size_t)(b << 11) << 2);
    {
        const float4* src = (const float4*)FDDb;
        fdpq[t] = src[t];           fdpq[t + 512]  = src[t + 512];
        fdpq[t + 1024] = src[t + 1024]; fdpq[t + 1536] = src[t + 1536];
    }
    if (t < 256) {
        int r = t >> 4, seg = t & 15;
        const uint4* src = (const uint4*)(bm + ((size_t)((b << 11) + i0 + r)) * 32);
        *(uint4*)&bmt[r][seg * 4] = src[seg];
    }
    __syncthreads();

    const float fs0 = FS[(b << 11) + i0 + li];
    const float Ei0 = exp2f(fs0), Ei20 = exp2f(0.2f * fs0);
    const int irow0 = i0 + li;
    const u16* ofb = OW2f + (size_t)b * 4 * 64 * 512;
    const int laneoff = li * 32 + q * 8;

    f32x4 zero = {0.f, 0.f, 0.f, 0.f};
    f32x4 acc[4];
#pragma unroll
    for (int fa = 0; fa < 4; fa++) acc[fa] = zero;
    float rs0 = 0.f;

    for (int s = 0; s < 8; ++s) {
        const int kblk = wv * 8 + s;
        const int kb = kblk * 32;
        const u16* ot = ofb + (size_t)kblk * 512 + laneoff;
        s16x8 xa0 = *(const s16x8*)(ot);
        s16x8 xa1 = *(const s16x8*)(ot + 64 * 512);
        s16x8 xa2 = *(const s16x8*)(ot + 128 * 512);
        s16x8 xa3 = *(const s16x8*)(ot + 192 * 512);
        const float4* fp4 = (const float4*)&fdpq[kb + q * 8];
        LOADQ8;
        u32 m0 = (bmt[li][kblk] >> (q * 8)) & 0xffu;
        const int jb = kb + q * 8;
        s16x8 bw0;
        MKW(fs0, Ei0, Ei20, irow0, m0, bw0, rs0);
        acc[0] = __builtin_amdgcn_mfma_f32_16x16x32_bf16(xa0, bw0, acc[0], 0, 0, 0);
        acc[1] = __builtin_amdgcn_mfma_f32_16x16x32_bf16(xa1, bw0, acc[1], 0, 0, 0);
        acc[2] = __builtin_amdgcn_mfma_f32_16x16x32_bf16(xa2, bw0, acc[2], 0, 0, 0);
        acc[3] = __builtin_amdgcn_mfma_f32_16x16x32_bf16(xa3, bw0, acc[3], 0, 0, 0);
    }
    rs0 += __shfl_xor(rs0, 16); rs0 += __shfl_xor(rs0, 32);
    if (l < 16) rsred[wv][l] = rs0;
    if (wv >= 4) {
#pragma unroll
        for (int fa = 0; fa < 4; fa++)
            *(float4*)&tp[wv - 4][li][fa * 16 + q * 4] =
                (float4){acc[fa][0], acc[fa][1], acc[fa][2], acc[fa][3]};
    }
    __syncthreads();
    if (wv < 4) {
#pragma unroll
        for (int fa = 0; fa < 4; fa++) {
            int co = fa * 16 + q * 4;
            float4 u0 = *(const float4*)&tp[wv][li][co];
            u0.x += acc[fa][0]; u0.y += acc[fa][1];
            u0.z += acc[fa][2]; u0.w += acc[fa][3];
            *(float4*)&tp[wv][li][co] = u0;
        }
    }
    __syncthreads();
    if (t < 16) {
        float rsum = 0.f;
#pragma unroll
        for (int w8 = 0; w8 < 8; w8++) rsum += rsred[w8][t];
        rscl[t] = FDDb[4 * (i0 + t) + 3] / fmaxf(rsum, 1e-30f);
    }
    {   // sum 4 slabs into tp[0]: 16 rows x 64 cols, float2 per thread
        int r = t >> 5, c = (t & 31) * 2;
        float2 v = *(const float2*)&tp[0][r][c];
#pragma unroll
        for (int w4 = 1; w4 < 4; w4++) {
            float2 u = *(const float2*)&tp[w4][r][c];
            v.x += u.x; v.y += u.y;
        }
        *(float2*)&tp[0][r][c] = v;
    }
    __syncthreads();
    {   // scale + bias, store node, write back for graph partial
        int r = t >> 5, c = (t & 31) * 2;
        float rsc = rscl[r];
        float2 v = *(const float2*)&tp[0][r][c];
        float2 bb = *(const float2*)&b2[c];
        v.x = v.x * rsc + bb.x; v.y = v.y * rsc + bb.y;
        *(float2*)&node[((size_t)(b << 11) + i0 + r) * NC + c] = v;
        *(float2*)&tp[0][r][c] = v;
    }
    __syncthreads();
    if (t < NC) {
        float s = 0.f;
#pragma unroll
        for (int r = 0; r < 16; ++r) s += tp[0][r][t];
        gpart[(((size_t)b * 128) + blockIdx.x) * NC + t] = s;
    }
}

// ---- graph scores: reduce per-block partials -------------------------------
__global__ void kgraph2(const float* __restrict__ gpart, float* __restrict__ graph) {
    int b = blockIdx.x;
    int c = threadIdx.x & 63, ch = threadIdx.x >> 6;
    float s = 0.f;
    for (int p = ch; p < 128; p += 4)
        s += gpart[((size_t)b * 128 + p) * NC + c];
    __shared__ float red[4][64];
    red[ch][c] = s;
    __syncthreads();
    if (ch == 0) graph[b * NC + c] = red[0][c] + red[1][c] + red[2][c] + red[3][c];
}

extern "C" void kernel_launch(void* const* d_in, const int* in_sizes, int n_in,
                              void* d_out, int out_size, void* d_ws, size_t ws_size,
                              hipStream_t stream) {
    const float* X   = (const float*)d_in[0];
    const float* A   = (const float*)d_in[1];
    const float* a1s = (const float*)d_in[2];
    const float* a1d = (const float*)d_in[3];
    const float* W1  = (const float*)d_in[4];
    const float* b1  = (const float*)d_in[5];
    const float* a2s = (const float*)d_in[6];
    const float* a2d = (const float*)d_in[7];
    const float* W2  = (const float*)d_in[8];
    const float* b2  = (const float*)d_in[9];

    float* node  = (float*)d_out;                 // [4][2048][64]
    float* graph = node + (size_t)NB * NN * NC;   // [4][64]

    char* w = (char*)d_ws;
    float* FS1  = (float*)w; w += NB * NN * 4;
    float* FDD1 = (float*)w; w += (size_t)NB * NN * 16;   // (fd, E, E2, d) quads
    float* FS2  = (float*)w; w += NB * NN * 4;
    float* FDD2 = (float*)w; w += (size_t)NB * NN * 16;   // (fd, E, E2, d) quads
    u64*  bm    = (u64*)w;  w += (size_t)NB * NN * 32 * 8;           // 2 MB
    u16*  XTf   = (u16*)w;  w += (size_t)NB * NF * NN * 2;           // 2 MB
    u16*  OW2f  = (u16*)w;  w += (size_t)NB * NC * NN * 2;           // 1 MB
    u16*  W1T   = (u16*)w;  w += NH * NF * 2;
    u16*  W2T   = (u16*)w;  w += NC * NH * 2;
    float* gpart = (float*)w; w += (size_t)NB * 128 * NC * 4;        // 128 KB

    kpre    <<<NB * 64 + 4 + NB * NN, 256, 0, stream>>>(X, A, a1s, a1d, W1, W2,
                                                        XTf, W1T, W2T, FS1,
                                                        FDD1, FDD2, bm);
    kdense1 <<<dim3(NN / 16, NB), 512, 0, stream>>>(bm, FS1, FDD1, XTf, W1T, W2T,
                                                    b1, a2s, a2d, FS2, FDD2, OW2f);
    kdense2 <<<dim3(NN / 16, NB), 512, 0, stream>>>(bm, FS2, FDD2, OW2f, b2,
                                                    node, gpart);
    kgraph2 <<<NB, 256, 0, stream>>>(gpart, graph);
}

// Round 18
// 56.416 us; speedup vs baseline: 1.3341x; 1.3341x over previous
//
#include <hip/hip_runtime.h>

// ---------------------------------------------------------------------------
// TwoLayerGCN on MI355X (gfx950).  B=4, N=2048, F=128, H=256, C=64.
//
//   d_i = rsqrt(nnz_i + 1) ; w_ij = [A_ij>0] exp(lrelu(fs_i+fd_j)) d_j (1+[i==j])
//   rs_i = sum_j [A_ij>0] exp(lrelu(fs_i+fd_j))
//   layer1: out1 = relu( (d_i/rs_i)(W@X)@W1 + b1 )
//   layer2: node = (d_i/rs_i) W2mat@(out1@W2) + b2 ; graph = sum_i node
//
// R9:  dense MFMA SpMM (operand swap, w in regs), zero barriers in K-loop.
// R15: de-dup MKW (8-way K-split). R16: factored exp2 + cvt_pk pack = 62.3us.
// R17: 16-row tiles FAILED (fixed per-block costs doubled). 32-row/1-block-CU
//      is the sweet spot; occupancy levers are exhausted.
// R18: revert to R16 + diag-check hoist: the (1+delta_ij) correction only
//      applies when kblk == i0>>5 (wave-uniform, <=1 of 8 steps/wave) ->
//      fast MKW (no diag, -16 VALU) on the other 7/8. Bit-exact math.
// ---------------------------------------------------------------------------

typedef __attribute__((ext_vector_type(8))) short  s16x8;
typedef __attribute__((ext_vector_type(4))) float  f32x4;
typedef unsigned short u16;
typedef unsigned int   u32;
typedef unsigned long long u64;

#define LOG2E 1.4426950408889634f
#define NB 4
#define NN 2048
#define NF 128
#define NH 256
#define NC 64

__device__ __forceinline__ u16 f2bf(float f) {
    u32 x = __builtin_bit_cast(u32, f);
    return (u16)((x + 0x7fffu + ((x >> 16) & 1u)) >> 16);
}

// ---- kpre: block-role dispatch ---------------------------------------------
// [0,256): X-tiles -> XTf (frag-tiled bf16) + layer1 dots (FS1, FDD1 quad 0-2).
// [256,260): W1T/W2T transposes.
// [260,260+8192): stats: A read (uint4) -> bm bitmask, d -> FDD1/FDD2 quad 3.
__global__ void kpre(const float* __restrict__ X, const float* __restrict__ A,
                     const float* __restrict__ a1s, const float* __restrict__ a1d,
                     const float* __restrict__ W1, const float* __restrict__ W2,
                     u16* __restrict__ XTf, u16* __restrict__ W1T,
                     u16* __restrict__ W2T, float* __restrict__ FS1,
                     float* __restrict__ FDD1, float* __restrict__ FDD2,
                     u64* __restrict__ bm) {
    const int bid = blockIdx.x;
    const int t = threadIdx.x;
    if (bid >= NB * 64 + 4) {                 // ---- stats role ----
        __shared__ int redi[4];
        int row = bid - (NB * 64 + 4);        // 0..8191
        const float* Arow = A + (size_t)row * NN;
        int l = t & 63, wv = t >> 6;
        int deg = 0;
#pragma unroll
        for (int e = 0; e < 2; e++) {
            uint4 av = *(const uint4*)&Arow[e * 1024 + t * 4];
            u32 nib = (av.x ? 1u : 0u) | (av.y ? 2u : 0u) |
                      (av.z ? 4u : 0u) | (av.w ? 8u : 0u);
            deg += (int)__popc(nib);
            u32 o1 = __shfl_xor(nib, 1);  u32 byt = nib | (o1 << 4);
            u32 o2 = __shfl_xor(byt, 2);  u32 h16 = byt | (o2 << 8);
            u32 o4 = __shfl_xor(h16, 4);  u32 w32 = h16 | (o4 << 16);
            u32 o8 = __shfl_xor(w32, 8);
            u64 w64 = (u64)w32 | ((u64)o8 << 32);
            if ((l & 15) == 0)
                bm[(size_t)row * 32 + e * 16 + wv * 4 + (l >> 4)] = w64;
        }
#pragma unroll
        for (int o = 32; o > 0; o >>= 1) deg += __shfl_down(deg, o);
        if (l == 0) redi[wv] = deg;
        __syncthreads();
        if (t == 0) {
            int s = redi[0] + redi[1] + redi[2] + redi[3];
            float d = rsqrtf((float)s + 1.0f);
            FDD1[4 * row + 3] = d;
            FDD2[4 * row + 3] = d;
        }
        return;
    }
    if (bid >= NB * 64) {                     // ---- weight role ----
        int tt = (bid - NB * 64) * 256 + t;
        for (int i = tt; i < NF * NH; i += 1024) {
            int k = i >> 8, c = i & 255;
            W1T[c * NF + k] = f2bf(W1[i]);
        }
        for (int i = tt; i < NH * NC; i += 1024) {
            int k = i >> 6, c = i & 63;
            W2T[c * NH + k] = f2bf(W2[i]);
        }
        return;
    }
    // ---- X role: 32 nodes (one k-block) ----
    __shared__ float tile[32][132];
    __shared__ float asb[NF], adb[NF];
    __shared__ float dred[32][8][2];
    const int b = bid >> 6, i0 = (bid & 63) * 32;
    if (t < 128) asb[t] = a1s[t];
    else         adb[t - 128] = a1d[t - 128];
    for (int i = t; i < 32 * NF / 4; i += 256) {
        int r = (i * 4) >> 7, c = (i * 4) & 127;
        *(float4*)&tile[r][c] = *(const float4*)&X[((size_t)b * NN + i0 + r) * NF + c];
    }
    __syncthreads();
    {   // layer1 dots
        int r = t >> 3, ch = t & 7;
        float ps = 0.f, pd = 0.f;
#pragma unroll
        for (int q = 0; q < 16; q++) {
            float x = tile[r][ch * 16 + q];
            ps += x * asb[ch * 16 + q];
            pd += x * adb[ch * 16 + q];
        }
        dred[r][ch][0] = ps; dred[r][ch][1] = pd;
    }
    {   // XTf frag-tiled write: frag f holds feats 16f..16f+15, tile [li][32 k]
        int f = t >> 5, li = (t >> 1) & 15, half = t & 1;
        __attribute__((aligned(16))) u16 tmp[16];
#pragma unroll
        for (int k = 0; k < 16; k++)
            tmp[k] = f2bf(tile[half * 16 + k][f * 16 + li]);
        u16* dst = XTf + ((size_t)(b * 8 + f) * 64 + (i0 >> 5)) * 512
                       + li * 32 + half * 16;
        int4* d4 = (int4*)dst;
        const int4* sv = (const int4*)tmp;
        d4[0] = sv[0]; d4[1] = sv[1];
    }
    __syncthreads();
    if (t < 64) {
        int r = t & 31, which = t >> 5;
        float s = 0.f;
#pragma unroll
        for (int ch = 0; ch < 8; ch++) s += dred[r][ch][which];
        int grow = (b << 11) + i0 + r;
        float sf = s * LOG2E;
        if (which == 0) FS1[grow] = sf;
        else {
            FDD1[4 * grow]     = sf;
            FDD1[4 * grow + 1] = exp2f(sf);
            FDD1[4 * grow + 2] = exp2f(0.2f * sf);
        }
    }
}

// fast MKW (no diagonal): 8 w values, j = jb..jb+7.
#define MKW_F(FS_, EI_, EI2_, M_, BW_, RS_) { \
    u32 pk0_, pk1_, pk2_, pk3_; \
    _Pragma("unroll") \
    for (int ee = 0; ee < 4; ee++) { \
        float s0_ = FS_ + fdv[2 * ee],     s1_ = FS_ + fdv[2 * ee + 1]; \
        float e0_ = (s0_ >= 0.f) ? EI_ * ev[2 * ee]     : EI2_ * e2v[2 * ee]; \
        float e1_ = (s1_ >= 0.f) ? EI_ * ev[2 * ee + 1] : EI2_ * e2v[2 * ee + 1]; \
        bool mk0 = (M_ >> (2 * ee)) & 1u, mk1 = (M_ >> (2 * ee + 1)) & 1u; \
        RS_ += mk0 ? e0_ : 0.f;  RS_ += mk1 ? e1_ : 0.f; \
        float w0_ = e0_ * dv[2 * ee], w1_ = e1_ * dv[2 * ee + 1]; \
        w0_ = mk0 ? w0_ : 0.f;  w1_ = mk1 ? w1_ : 0.f; \
        u32 pr_; \
        asm("v_cvt_pk_bf16_f32 %0, %1, %2" : "=v"(pr_) : "v"(w0_), "v"(w1_)); \
        if (ee == 0) pk0_ = pr_; else if (ee == 1) pk1_ = pr_; \
        else if (ee == 2) pk2_ = pr_; else pk3_ = pr_; \
    } \
    uint4 pku_ = {pk0_, pk1_, pk2_, pk3_}; \
    BW_ = __builtin_bit_cast(s16x8, pku_); }

// full MKW (with diagonal x2), used only when kblk == i0>>5.
#define MKW_D(FS_, EI_, EI2_, IR_, M_, BW_, RS_) { \
    u32 pk0_, pk1_, pk2_, pk3_; \
    _Pragma("unroll") \
    for (int ee = 0; ee < 4; ee++) { \
        float s0_ = FS_ + fdv[2 * ee],     s1_ = FS_ + fdv[2 * ee + 1]; \
        float e0_ = (s0_ >= 0.f) ? EI_ * ev[2 * ee]     : EI2_ * e2v[2 * ee]; \
        float e1_ = (s1_ >= 0.f) ? EI_ * ev[2 * ee + 1] : EI2_ * e2v[2 * ee + 1]; \
        bool mk0 = (M_ >> (2 * ee)) & 1u, mk1 = (M_ >> (2 * ee + 1)) & 1u; \
        RS_ += mk0 ? e0_ : 0.f;  RS_ += mk1 ? e1_ : 0.f; \
        float w0_ = e0_ * dv[2 * ee], w1_ = e1_ * dv[2 * ee + 1]; \
        if (jb + 2 * ee == IR_)     w0_ *= 2.f; \
        if (jb + 2 * ee + 1 == IR_) w1_ *= 2.f; \
        w0_ = mk0 ? w0_ : 0.f;  w1_ = mk1 ? w1_ : 0.f; \
        u32 pr_; \
        asm("v_cvt_pk_bf16_f32 %0, %1, %2" : "=v"(pr_) : "v"(w0_), "v"(w1_)); \
        if (ee == 0) pk0_ = pr_; else if (ee == 1) pk1_ = pr_; \
        else if (ee == 2) pk2_ = pr_; else pk3_ = pr_; \
    } \
    uint4 pku_ = {pk0_, pk1_, pk2_, pk3_}; \
    BW_ = __builtin_bit_cast(s16x8, pku_); }

#define LOADQ8 \
    float fdv[8], ev[8], e2v[8], dv[8]; \
    _Pragma("unroll") \
    for (int e = 0; e < 8; e++) { \
        float4 ffq = fp4[e]; \
        fdv[e] = ffq.x; ev[e] = ffq.y; e2v[e] = ffq.z; dv[e] = ffq.w; }

// ---- kdense1: layer1 SpMM (8-way K-split) + epilogue -----------------------
__global__ __launch_bounds__(512) void kdense1(
    const u64* __restrict__ bm, const float* __restrict__ FS,
    const float* __restrict__ FDD, const u16* __restrict__ XTf,
    const u16* __restrict__ W1T, const u16* __restrict__ W2T,
    const float* __restrict__ b1, const float* __restrict__ a2s,
    const float* __restrict__ a2d, float* __restrict__ FS2,
    float* __restrict__ FDD2, u16* __restrict__ OW2f) {
    const int b = blockIdx.y;
    const int i0 = blockIdx.x * 32;
    const int t = threadIdx.x, wv = t >> 6, l = t & 63;
    const int li = l & 15, q = l >> 4;

    __shared__ __attribute__((aligned(16))) float tpart[4][32][132];  // 67.6KB
    float* o1 = &tpart[0][0][0];            // [32][260] aliases slabs 0-1
    __shared__ __attribute__((aligned(16))) float4 fdpq[2048];        // 32KB
    __shared__ __attribute__((aligned(16))) u32 bmt[32][68];          // 8.7KB
    __shared__ float rsred[8][2][16];
    __shared__ float rscl[32];
    __shared__ float dredp[1024];

    const float* FDDb = FDD + ((size_t)(b << 11) << 2);
    {   // stage fd/E/E2/d quad panel
        const float4* src = (const float4*)FDDb;
        fdpq[t] = src[t];           fdpq[t + 512]  = src[t + 512];
        fdpq[t + 1024] = src[t + 1024]; fdpq[t + 1536] = src[t + 1536];
    }
    {   // stage bm tile: 32 rows x 256B, padded stride 68 u32
        int r = t >> 4, seg = t & 15;
        const uint4* src = (const uint4*)(bm + ((size_t)((b << 11) + i0 + r)) * 32);
        *(uint4*)&bmt[r][seg * 4] = src[seg];
    }
    __syncthreads();

    const float fs0 = FS[(b << 11) + i0 + li];
    const float fs1 = FS[(b << 11) + i0 + 16 + li];
    const float Ei0 = exp2f(fs0), Ei20 = exp2f(0.2f * fs0);
    const float Ei1 = exp2f(fs1), Ei21 = exp2f(0.2f * fs1);
    const int irow0 = i0 + li, irow1 = i0 + 16 + li;
    const int dblk = i0 >> 5;
    const u16* xfb = XTf + (size_t)b * 8 * 64 * 512;
    const int laneoff = li * 32 + q * 8;      // lane offset within 1KB frag tile

    f32x4 zero = {0.f, 0.f, 0.f, 0.f};
    f32x4 acc[8][2];
#pragma unroll
    for (int fa = 0; fa < 8; fa++) { acc[fa][0] = zero; acc[fa][1] = zero; }
    float rs0 = 0.f, rs1 = 0.f;

    for (int st = 0; st < 8; ++st) {
        const int kblk = st * 8 + wv;         // unique k-block per wave
        const int kb = kblk * 32;
        const u16* xt = xfb + (size_t)kblk * 512 + laneoff;
        s16x8 xa0 = *(const s16x8*)(xt);
        s16x8 xa1 = *(const s16x8*)(xt + 1 * 64 * 512);
        s16x8 xa2 = *(const s16x8*)(xt + 2 * 64 * 512);
        s16x8 xa3 = *(const s16x8*)(xt + 3 * 64 * 512);
        s16x8 xa4 = *(const s16x8*)(xt + 4 * 64 * 512);
        s16x8 xa5 = *(const s16x8*)(xt + 5 * 64 * 512);
        s16x8 xa6 = *(const s16x8*)(xt + 6 * 64 * 512);
        s16x8 xa7 = *(const s16x8*)(xt + 7 * 64 * 512);
        const float4* fp4 = (const float4*)&fdpq[kb + q * 8];
        LOADQ8;
        u32 m0 = (bmt[li][kblk]      >> (q * 8)) & 0xffu;
        u32 m1 = (bmt[16 + li][kblk] >> (q * 8)) & 0xffu;
        const int jb = kb + q * 8;
        s16x8 bw0, bw1;
        if (kblk == dblk) {
            MKW_D(fs0, Ei0, Ei20, irow0, m0, bw0, rs0);
            MKW_D(fs1, Ei1, Ei21, irow1, m1, bw1, rs1);
        } else {
            MKW_F(fs0, Ei0, Ei20, m0, bw0, rs0);
            MKW_F(fs1, Ei1, Ei21, m1, bw1, rs1);
        }
        acc[0][0] = __builtin_amdgcn_mfma_f32_16x16x32_bf16(xa0, bw0, acc[0][0], 0, 0, 0);
        acc[1][0] = __builtin_amdgcn_mfma_f32_16x16x32_bf16(xa1, bw0, acc[1][0], 0, 0, 0);
        acc[2][0] = __builtin_amdgcn_mfma_f32_16x16x32_bf16(xa2, bw0, acc[2][0], 0, 0, 0);
        acc[3][0] = __builtin_amdgcn_mfma_f32_16x16x32_bf16(xa3, bw0, acc[3][0], 0, 0, 0);
        acc[4][0] = __builtin_amdgcn_mfma_f32_16x16x32_bf16(xa4, bw0, acc[4][0], 0, 0, 0);
        acc[5][0] = __builtin_amdgcn_mfma_f32_16x16x32_bf16(xa5, bw0, acc[5][0], 0, 0, 0);
        acc[6][0] = __builtin_amdgcn_mfma_f32_16x16x32_bf16(xa6, bw0, acc[6][0], 0, 0, 0);
        acc[7][0] = __builtin_amdgcn_mfma_f32_16x16x32_bf16(xa7, bw0, acc[7][0], 0, 0, 0);
        acc[0][1] = __builtin_amdgcn_mfma_f32_16x16x32_bf16(xa0, bw1, acc[0][1], 0, 0, 0);
        acc[1][1] = __builtin_amdgcn_mfma_f32_16x16x32_bf16(xa1, bw1, acc[1][1], 0, 0, 0);
        acc[2][1] = __builtin_amdgcn_mfma_f32_16x16x32_bf16(xa2, bw1, acc[2][1], 0, 0, 0);
        acc[3][1] = __builtin_amdgcn_mfma_f32_16x16x32_bf16(xa3, bw1, acc[3][1], 0, 0, 0);
        acc[4][1] = __builtin_amdgcn_mfma_f32_16x16x32_bf16(xa4, bw1, acc[4][1], 0, 0, 0);
        acc[5][1] = __builtin_amdgcn_mfma_f32_16x16x32_bf16(xa5, bw1, acc[5][1], 0, 0, 0);
        acc[6][1] = __builtin_amdgcn_mfma_f32_16x16x32_bf16(xa6, bw1, acc[6][1], 0, 0, 0);
        acc[7][1] = __builtin_amdgcn_mfma_f32_16x16x32_bf16(xa7, bw1, acc[7][1], 0, 0, 0);
    }
    rs0 += __shfl_xor(rs0, 16); rs0 += __shfl_xor(rs0, 32);
    rs1 += __shfl_xor(rs1, 16); rs1 += __shfl_xor(rs1, 32);
    if (l < 16) { rsred[wv][0][l] = rs0; rsred[wv][1][l] = rs1; }
    // two-round k-reduction: waves 4-7 write slabs 0-3, waves 0-3 accumulate
    if (wv >= 4) {
#pragma unroll
        for (int fa = 0; fa < 8; fa++) {
            int co = fa * 16 + q * 4;
            *(float4*)&tpart[wv - 4][li][co] =
                (float4){acc[fa][0][0], acc[fa][0][1], acc[fa][0][2], acc[fa][0][3]};
            *(float4*)&tpart[wv - 4][16 + li][co] =
                (float4){acc[fa][1][0], acc[fa][1][1], acc[fa][1][2], acc[fa][1][3]};
        }
    }
    __syncthreads();
    if (wv < 4) {
#pragma unroll
        for (int fa = 0; fa < 8; fa++) {
            int co = fa * 16 + q * 4;
            float4 u0 = *(const float4*)&tpart[wv][li][co];
            float4 u1 = *(const float4*)&tpart[wv][16 + li][co];
            u0.x += acc[fa][0][0]; u0.y += acc[fa][0][1];
            u0.z += acc[fa][0][2]; u0.w += acc[fa][0][3];
            u1.x += acc[fa][1][0]; u1.y += acc[fa][1][1];
            u1.z += acc[fa][1][2]; u1.w += acc[fa][1][3];
            *(float4*)&tpart[wv][li][co] = u0;
            *(float4*)&tpart[wv][16 + li][co] = u1;
        }
    }
    __syncthreads();
    if (t < 32) {
        float rsum = 0.f;
#pragma unroll
        for (int w8 = 0; w8 < 8; w8++) rsum += rsred[w8][t >> 4][t & 15];
        rscl[t] = FDDb[4 * (i0 + t) + 3] / fmaxf(rsum, 1e-30f);
    }
    {   // sum 4 slabs into tpart[0]: 4096 floats, 8 per thread
        int r = t >> 4, c0 = (t & 15) * 8;
#pragma unroll
        for (int hx = 0; hx < 2; hx++) {
            int c = c0 + hx * 4;
            float4 v0 = *(const float4*)&tpart[0][r][c];
            float4 v1 = *(const float4*)&tpart[1][r][c];
            float4 v2 = *(const float4*)&tpart[2][r][c];
            float4 v3 = *(const float4*)&tpart[3][r][c];
            v0.x += v1.x + v2.x + v3.x; v0.y += v1.y + v2.y + v3.y;
            v0.z += v1.z + v2.z + v3.z; v0.w += v1.w + v2.w + v3.w;
            *(float4*)&tpart[0][r][c] = v0;
        }
    }
    __syncthreads();
    // ---- epilogue: GEMM1 T@W1 -> o1 ; dots2 ; GEMM2 o1@W2 -> OW2f ---------
    const int c0w = wv * 32;
    f32x4 p00 = zero, p01 = zero, p10 = zero, p11 = zero;
    for (int k2 = 0; k2 < 4; ++k2) {
        s16x8 a2f[2];
#pragma unroll
        for (int mt = 0; mt < 2; ++mt) {
            const float* tp = &tpart[0][mt * 16 + li][k2 * 32 + q * 8];
            float4 t0 = *(const float4*)tp;
            float4 t1 = *(const float4*)(tp + 4);
            s16x8 aa;
            aa[0] = (short)f2bf(t0.x); aa[1] = (short)f2bf(t0.y);
            aa[2] = (short)f2bf(t0.z); aa[3] = (short)f2bf(t0.w);
            aa[4] = (short)f2bf(t1.x); aa[5] = (short)f2bf(t1.y);
            aa[6] = (short)f2bf(t1.z); aa[7] = (short)f2bf(t1.w);
            a2f[mt] = aa;
        }
        s16x8 w0 = *(const s16x8*)&W1T[(size_t)(c0w + li) * NF + k2 * 32 + q * 8];
        s16x8 w1 = *(const s16x8*)&W1T[(size_t)(c0w + 16 + li) * NF + k2 * 32 + q * 8];
        p00 = __builtin_amdgcn_mfma_f32_16x16x32_bf16(a2f[0], w0, p00, 0, 0, 0);
        p01 = __builtin_amdgcn_mfma_f32_16x16x32_bf16(a2f[0], w1, p01, 0, 0, 0);
        p10 = __builtin_amdgcn_mfma_f32_16x16x32_bf16(a2f[1], w0, p10, 0, 0, 0);
        p11 = __builtin_amdgcn_mfma_f32_16x16x32_bf16(a2f[1], w1, p11, 0, 0, 0);
    }
    __syncthreads();   // tpart[0] reads done; o1 (same region) now writable
#pragma unroll
    for (int mt = 0; mt < 2; ++mt) {
        f32x4 pa = mt ? p10 : p00;
        f32x4 pb = mt ? p11 : p01;
#pragma unroll
        for (int r = 0; r < 4; r++) {
            int rr = mt * 16 + q * 4 + r;
            float rsc = rscl[rr];
            int ca = c0w + li, cb2 = c0w + 16 + li;
            o1[rr * 260 + ca]  = fmaxf(pa[r] * rsc + b1[ca], 0.f);
            o1[rr * 260 + cb2] = fmaxf(pb[r] * rsc + b1[cb2], 0.f);
        }
    }
    __syncthreads();
    {   // dots2: 32 rows x 16 segs of 16 cols
        int r = t >> 4, seg = t & 15;
        float ps = 0.f, pd = 0.f;
#pragma unroll
        for (int qq = 0; qq < 4; qq++) {
            float4 xv = *(const float4*)&o1[r * 260 + seg * 16 + qq * 4];
            float4 sv = *(const float4*)&a2s[seg * 16 + qq * 4];
            float4 dv2 = *(const float4*)&a2d[seg * 16 + qq * 4];
            ps += xv.x * sv.x + xv.y * sv.y + xv.z * sv.z + xv.w * sv.w;
            pd += xv.x * dv2.x + xv.y * dv2.y + xv.z * dv2.z + xv.w * dv2.w;
        }
        dredp[(r * 16 + seg) * 2]     = ps;
        dredp[(r * 16 + seg) * 2 + 1] = pd;
    }
    {   // GEMM2 -> OW2f frag tiles: frag nt (c-rows), k = nodes of this block
        const int mt = wv & 1, nt = wv >> 1;
        f32x4 q0 = zero;
        for (int k2 = 0; k2 < 8; ++k2) {
            int kc = k2 * 32 + q * 8;
            const float* op = &o1[(mt * 16 + li) * 260 + kc];
            float4 v0 = *(const float4*)op;
            float4 v1 = *(const float4*)(op + 4);
            s16x8 aa;
            aa[0] = (short)f2bf(v0.x); aa[1] = (short)f2bf(v0.y);
            aa[2] = (short)f2bf(v0.z); aa[3] = (short)f2bf(v0.w);
            aa[4] = (short)f2bf(v1.x); aa[5] = (short)f2bf(v1.y);
            aa[6] = (short)f2bf(v1.z); aa[7] = (short)f2bf(v1.w);
            s16x8 bb = *(const s16x8*)&W2T[(size_t)(nt * 16 + li) * NH + kc];
            q0 = __builtin_amdgcn_mfma_f32_16x16x32_bf16(aa, bb, q0, 0, 0, 0);
        }
        u16* dst = OW2f + ((size_t)(b * 4 + nt) * 64 + (i0 >> 5)) * 512
                        + li * 32 + mt * 16 + q * 4;
        uint2 pk;
        pk.x = (u32)f2bf(q0[0]) | ((u32)f2bf(q0[1]) << 16);
        pk.y = (u32)f2bf(q0[2]) | ((u32)f2bf(q0[3]) << 16);
        *(uint2*)dst = pk;
    }
    __syncthreads();
    if (t < 64) {
        int r = t & 31, which = t >> 5;
        float s = 0.f;
#pragma unroll
        for (int seg = 0; seg < 16; ++seg) s += dredp[(r * 16 + seg) * 2 + which];
        int grow = (b << 11) + i0 + r;
        float sf = s * LOG2E;
        if (which == 0) FS2[grow] = sf;
        else {
            FDD2[4 * grow]     = sf;
            FDD2[4 * grow + 1] = exp2f(sf);
            FDD2[4 * grow + 2] = exp2f(0.2f * sf);
        }
    }
}

// ---- kdense2: layer2 SpMM; node + graph partials ---------------------------
__global__ __launch_bounds__(512) void kdense2(
    const u64* __restrict__ bm, const float* __restrict__ FS,
    const float* __restrict__ FDD, const u16* __restrict__ OW2f,
    const float* __restrict__ b2, float* __restrict__ node,
    float* __restrict__ gpart) {
    const int b = blockIdx.y;
    const int i0 = blockIdx.x * 32;
    const int t = threadIdx.x, wv = t >> 6, l = t & 63;
    const int li = l & 15, q = l >> 4;

    __shared__ __attribute__((aligned(16))) float tp[4][32][68];      // 34.8KB
    __shared__ __attribute__((aligned(16))) float4 fdpq[2048];        // 32KB
    __shared__ __attribute__((aligned(16))) u32 bmt[32][68];          // 8.7KB
    __shared__ float rsred[8][2][16];
    __shared__ float rscl[32];

    const float* FDDb = FDD + ((size_t)(b << 11) << 2);
    {
        const float4* src = (const float4*)FDDb;
        fdpq[t] = src[t];           fdpq[t + 512]  = src[t + 512];
        fdpq[t + 1024] = src[t + 1024]; fdpq[t + 1536] = src[t + 1536];
    }
    {
        int r = t >> 4, seg = t & 15;
        const uint4* src = (const uint4*)(bm + ((size_t)((b << 11) + i0 + r)) * 32);
        *(uint4*)&bmt[r][seg * 4] = src[seg];
    }
    __syncthreads();

    const float fs0 = FS[(b << 11) + i0 + li];
    const float fs1 = FS[(b << 11) + i0 + 16 + li];
    const float Ei0 = exp2f(fs0), Ei20 = exp2f(0.2f * fs0);
    const float Ei1 = exp2f(fs1), Ei21 = exp2f(0.2f * fs1);
    const int irow0 = i0 + li, irow1 = i0 + 16 + li;
    const int dblk = i0 >> 5;
    const u16* ofb = OW2f + (size_t)b * 4 * 64 * 512;
    const int laneoff = li * 32 + q * 8;

    f32x4 zero = {0.f, 0.f, 0.f, 0.f};
    f32x4 acc[4][2];
#pragma unroll
    for (int fa = 0; fa < 4; fa++) { acc[fa][0] = zero; acc[fa][1] = zero; }
    float rs0 = 0.f, rs1 = 0.f;

    for (int s = 0; s < 8; ++s) {
        const int kblk = wv * 8 + s;
        const int kb = kblk * 32;
        const u16* ot = ofb + (size_t)kblk * 512 + laneoff;
        s16x8 xa0 = *(const s16x8*)(ot);
        s16x8 xa1 = *(const s16x8*)(ot + 64 * 512);
        s16x8 xa2 = *(const s16x8*)(ot + 128 * 512);
        s16x8 xa3 = *(const s16x8*)(ot + 192 * 512);
        const float4* fp4 = (const float4*)&fdpq[kb + q * 8];
        LOADQ8;
        u32 m0 = (bmt[li][kblk]      >> (q * 8)) & 0xffu;
        u32 m1 = (bmt[16 + li][kblk] >> (q * 8)) & 0xffu;
        const int jb = kb + q * 8;
        s16x8 bw0, bw1;
        if (kblk == dblk) {
            MKW_D(fs0, Ei0, Ei20, irow0, m0, bw0, rs0);
            MKW_D(fs1, Ei1, Ei21, irow1, m1, bw1, rs1);
        } else {
            MKW_F(fs0, Ei0, Ei20, m0, bw0, rs0);
            MKW_F(fs1, Ei1, Ei21, m1, bw1, rs1);
        }
        acc[0][0] = __builtin_amdgcn_mfma_f32_16x16x32_bf16(xa0, bw0, acc[0][0], 0, 0, 0);
        acc[1][0] = __builtin_amdgcn_mfma_f32_16x16x32_bf16(xa1, bw0, acc[1][0], 0, 0, 0);
        acc[2][0] = __builtin_amdgcn_mfma_f32_16x16x32_bf16(xa2, bw0, acc[2][0], 0, 0, 0);
        acc[3][0] = __builtin_amdgcn_mfma_f32_16x16x32_bf16(xa3, bw0, acc[3][0], 0, 0, 0);
        acc[0][1] = __builtin_amdgcn_mfma_f32_16x16x32_bf16(xa0, bw1, acc[0][1], 0, 0, 0);
        acc[1][1] = __builtin_amdgcn_mfma_f32_16x16x32_bf16(xa1, bw1, acc[1][1], 0, 0, 0);
        acc[2][1] = __builtin_amdgcn_mfma_f32_16x16x32_bf16(xa2, bw1, acc[2][1], 0, 0, 0);
        acc[3][1] = __builtin_amdgcn_mfma_f32_16x16x32_bf16(xa3, bw1, acc[3][1], 0, 0, 0);
    }
    rs0 += __shfl_xor(rs0, 16); rs0 += __shfl_xor(rs0, 32);
    rs1 += __shfl_xor(rs1, 16); rs1 += __shfl_xor(rs1, 32);
    if (l < 16) { rsred[wv][0][l] = rs0; rsred[wv][1][l] = rs1; }
    if (wv >= 4) {
#pragma unroll
        for (int fa = 0; fa < 4; fa++) {
            *(float4*)&tp[wv - 4][li][fa * 16 + q * 4] =
                (float4){acc[fa][0][0], acc[fa][0][1], acc[fa][0][2], acc[fa][0][3]};
            *(float4*)&tp[wv - 4][16 + li][fa * 16 + q * 4] =
                (float4){acc[fa][1][0], acc[fa][1][1], acc[fa][1][2], acc[fa][1][3]};
        }
    }
    __syncthreads();
    if (wv < 4) {
#pragma unroll
        for (int fa = 0; fa < 4; fa++) {
            int co = fa * 16 + q * 4;
            float4 u0 = *(const float4*)&tp[wv][li][co];
            float4 u1 = *(const float4*)&tp[wv][16 + li][co];
            u0.x += acc[fa][0][0]; u0.y += acc[fa][0][1];
            u0.z += acc[fa][0][2]; u0.w += acc[fa][0][3];
            u1.x += acc[fa][1][0]; u1.y += acc[fa][1][1];
            u1.z += acc[fa][1][2]; u1.w += acc[fa][1][3];
            *(float4*)&tp[wv][li][co] = u0;
            *(float4*)&tp[wv][16 + li][co] = u1;
        }
    }
    __syncthreads();
    if (t < 32) {
        float rsum = 0.f;
#pragma unroll
        for (int w8 = 0; w8 < 8; w8++) rsum += rsred[w8][t >> 4][t & 15];
        rscl[t] = FDDb[4 * (i0 + t) + 3] / fmaxf(rsum, 1e-30f);
    }
    {   // sum 4 slabs into tp[0]
        int r = t >> 4, c0 = (t & 15) * 4;
        float4 v = *(const float4*)&tp[0][r][c0];
#pragma unroll
        for (int w4 = 1; w4 < 4; w4++) {
            float4 u = *(const float4*)&tp[w4][r][c0];
            v.x += u.x; v.y += u.y; v.z += u.z; v.w += u.w;
        }
        *(float4*)&tp[0][r][c0] = v;
    }
    __syncthreads();
    {   // scale + bias, store node, write back for graph partial
        int r = t >> 4, c0 = (t & 15) * 4;
        float rsc = rscl[r];
        float4 v = *(const float4*)&tp[0][r][c0];
        float4 bb = *(const float4*)&b2[c0];
        v.x = v.x * rsc + bb.x; v.y = v.y * rsc + bb.y;
        v.z = v.z * rsc + bb.z; v.w = v.w * rsc + bb.w;
        *(float4*)&node[((size_t)(b << 11) + i0 + r) * NC + c0] = v;
        *(float4*)&tp[0][r][c0] = v;
    }
    __syncthreads();
    if (t < NC) {
        float s = 0.f;
#pragma unroll
        for (int r = 0; r < 32; ++r) s += tp[0][r][t];
        gpart[(((size_t)b * 64) + blockIdx.x) * NC + t] = s;
    }
}

// ---- graph scores: reduce per-block partials -------------------------------
__global__ void kgraph2(const float* __restrict__ gpart, float* __restrict__ graph) {
    int b = blockIdx.x;
    int c = threadIdx.x & 63, ch = threadIdx.x >> 6;
    float s = 0.f;
    for (int p = ch; p < 64; p += 4)
        s += gpart[((size_t)b * 64 + p) * NC + c];
    __shared__ float red[4][64];
    red[ch][c] = s;
    __syncthreads();
    if (ch == 0) graph[b * NC + c] = red[0][c] + red[1][c] + red[2][c] + red[3][c];
}

extern "C" void kernel_launch(void* const* d_in, const int* in_sizes, int n_in,
                              void* d_out, int out_size, void* d_ws, size_t ws_size,
                              hipStream_t stream) {
    const float* X   = (const float*)d_in[0];
    const float* A   = (const float*)d_in[1];
    const float* a1s = (const float*)d_in[2];
    const float* a1d = (const float*)d_in[3];
    const float* W1  = (const float*)d_in[4];
    const float* b1  = (const float*)d_in[5];
    const float* a2s = (const float*)d_in[6];
    const float* a2d = (const float*)d_in[7];
    const float* W2  = (const float*)d_in[8];
    const float* b2  = (const float*)d_in[9];

    float* node  = (float*)d_out;                 // [4][2048][64]
    float* graph = node + (size_t)NB * NN * NC;   // [4][64]

    char* w = (char*)d_ws;
    float* FS1  = (float*)w; w += NB * NN * 4;
    float* FDD1 = (float*)w; w += (size_t)NB * NN * 16;   // (fd, E, E2, d) quads
    float* FS2  = (float*)w; w += NB * NN * 4;
    float* FDD2 = (float*)w; w += (size_t)NB * NN * 16;   // (fd, E, E2, d) quads
    u64*  bm    = (u64*)w;  w += (size_t)NB * NN * 32 * 8;           // 2 MB
    u16*  XTf   = (u16*)w;  w += (size_t)NB * NF * NN * 2;           // 2 MB
    u16*  OW2f  = (u16*)w;  w += (size_t)NB * NC * NN * 2;           // 1 MB
    u16*  W1T   = (u16*)w;  w += NH * NF * 2;
    u16*  W2T   = (u16*)w;  w += NC * NH * 2;
    float* gpart = (float*)w; w += (size_t)NB * 64 * NC * 4;         // 64 KB

    kpre    <<<NB * 64 + 4 + NB * NN, 256, 0, stream>>>(X, A, a1s, a1d, W1, W2,
                                                        XTf, W1T, W2T, FS1,
                                                        FDD1, FDD2, bm);
    kdense1 <<<dim3(NN / 32, NB), 512, 0, stream>>>(bm, FS1, FDD1, XTf, W1T, W2T,
                                                    b1, a2s, a2d, FS2, FDD2, OW2f);
    kdense2 <<<dim3(NN / 32, NB), 512, 0, stream>>>(bm, FS2, FDD2, OW2f, b2,
                                                    node, gpart);
    kgraph2 <<<NB, 256, 0, stream>>>(gpart, graph);
}